// Round 15
// baseline (317.173 us; speedup 1.0000x reference)
//
#include <hip/hip_runtime.h>
#include <math.h>

#define SEQ   2048
#define NHEAD 16
#define HD    64
#define BSZ   2
#define MTOT  (BSZ*SEQ)   // 4096

#define LOG2E    1.4426950408889634f
#define C_SCALE  0.18033688011112043f    // 0.125 * log2(e)
#define C_MOFF  -23.083120654223414f     // -16 * log2(e)

typedef __bf16 bf16x8 __attribute__((ext_vector_type(8)));
typedef short  s16x8  __attribute__((ext_vector_type(8)));
typedef short  s16x4  __attribute__((ext_vector_type(4)));
typedef float  f32x4  __attribute__((ext_vector_type(4)));

// fp32 -> bf16 RNE, hardware cvt. Use in issue-bound kernels (gemm epilogue,
// prep).
__device__ __forceinline__ short f2bf(float x) {
    return __builtin_bit_cast(short, (__bf16)x);
}
// fp32 -> bf16 RNE, bit-math. Used in the LATENCY-BOUND attn kernel
// (2 waves/SIMD): extra int ops fill trans/LDS latency for free.
// attn ledger: bitmath/nosp 3-term = 117-119 (9 containers) — every
// work-removal variant regressed (hwcvt +26, setprio +8, 1-term QK +16:
// the "redundant" ops were covering mask-load/trans latency).
__device__ __forceinline__ short f2bf_bm(float x) {
    unsigned u = __builtin_bit_cast(unsigned, x);
    u = (u + 0x7fffu + ((u >> 16) & 1u)) >> 16;
    return (short)u;
}
__device__ __forceinline__ float bf2f(short h) {
    unsigned u = ((unsigned)(unsigned short)h) << 16;
    return __builtin_bit_cast(float, u);
}

// async global->LDS 16B: dest = wave-uniform lds base + lane*16
__device__ __forceinline__ void gl_lds16(const short* g, short* l) {
    __builtin_amdgcn_global_load_lds(
        (const __attribute__((address_space(1))) unsigned int*)g,
        (__attribute__((address_space(3))) unsigned int*)l, 16, 0, 0);
}

// ---------------------------------------------------------------------------
// Transpose+split one 32x32 tile: W[K,N] fp32 -> Th (+Tl if non-null)
// [N,K] bf16 hi/lo
// ---------------------------------------------------------------------------
__device__ __forceinline__ void tsplit_tile(const float* __restrict__ W,
    short* __restrict__ Th, short* __restrict__ Tl,
    int K, int N, int k0, int n0, float (*T)[33], int t)
{
    {
        const int kl = t >> 3;
        const int nl = (t & 7) * 4;
        const float4 v = *(const float4*)&W[(size_t)(k0 + kl) * N + n0 + nl];
        T[nl + 0][kl] = v.x; T[nl + 1][kl] = v.y;
        T[nl + 2][kl] = v.z; T[nl + 3][kl] = v.w;
    }
    __syncthreads();
    {
        const int nl = t >> 3;
        const int kl = (t & 7) * 4;
        s16x4 h, l;
        #pragma unroll
        for (int c = 0; c < 4; ++c) {
            const float x = T[nl][kl + c];
            const short hb = f2bf(x);
            h[c] = hb;
            l[c] = f2bf(x - bf2f(hb));
        }
        const size_t o = (size_t)(n0 + nl) * K + k0 + kl;
        *(s16x4*)&Th[o] = h;
        if (Tl) *(s16x4*)&Tl[o] = l;
    }
}

// ---------------------------------------------------------------------------
// prep: [0,1024) seq -> seqh (bf16 hi only);
//       [1024,4096) Wqkv hi only; [4096,6144) W1 hi only;
//       [6144,8192) W2 hi only. (r13 structure — r14's P1-fusion was
//       neutral within noise; keeping the simpler proven form.)
// ---------------------------------------------------------------------------
__global__ __launch_bounds__(256)
void prep_kernel(const float* __restrict__ seq, short* __restrict__ seqh,
                 const float* __restrict__ Wqkv, short* __restrict__ WtQh,
                 const float* __restrict__ W1, short* __restrict__ Wt1h,
                 const float* __restrict__ W2, short* __restrict__ Wt2h)
{
    __shared__ float T[32][33];
    const int t = threadIdx.x;
    const int bid = blockIdx.x;
    if (bid < 1024) {
        const size_t base = (size_t)bid * 4096 + (size_t)t * 16;
        #pragma unroll
        for (int c = 0; c < 4; ++c) {
            const float4 v = *(const float4*)&seq[base + c * 4];
            s16x4 h;
            h[0] = f2bf(v.x); h[1] = f2bf(v.y); h[2] = f2bf(v.z); h[3] = f2bf(v.w);
            *(s16x4*)&seqh[base + c * 4] = h;
        }
    } else if (bid < 4096) {
        const int idx = bid - 1024;
        tsplit_tile(Wqkv, WtQh, nullptr, 1024, 3072, (idx & 31) * 32, (idx >> 5) * 32, T, t);
    } else if (bid < 6144) {
        const int idx = bid - 4096;
        tsplit_tile(W1, Wt1h, nullptr, 1024, 2048, (idx & 31) * 32, (idx >> 5) * 32, T, t);
    } else {
        const int idx = bid - 6144;
        tsplit_tile(W2, Wt2h, nullptr, 2048, 1024, (idx & 63) * 32, (idx >> 6) * 32, T, t);
    }
}

// ---------------------------------------------------------------------------
// split MFMA GEMM v10 = r13's BK=32 double-buffered 1-term kernel with
// __launch_bounds__(256, 4):
//   1-term dropped LDS to 32KB (A 16 + B 16) -> LDS allows 5 blocks/CU;
//   (256,2) left the register allocator free to exceed 128 VGPR, capping
//   residency at <=3. (256,4) caps VGPR at 128 -> 4 blocks/CU = 4
//   waves/SIMD, doubling the TLP hiding staging latency. Pressure est:
//   acc 64 + frags 32 + addr ~20 = ~116 < 128 (WRITE_SIZE = spill tripwire).
// All GEMMs 1-term (FFN proven r11, QKV proven r13; absmax pinned 2^-9).
// V direct-transposed store in VT epilogue (r10, util_kernel eliminated).
// OMODE: 0 fp32 out, 1 split hi/lo out, 2 hi-only out. ACT 1: SiLU.
// ---------------------------------------------------------------------------
template<int ACT, int OMODE, int VT, int NB, bool TWOB>
__global__ __launch_bounds__(256, 4)
void gemm2(const short* __restrict__ Ahg,
           const short* __restrict__ Bhg, const short* __restrict__ Blg,
           const float* __restrict__ bias,
           float* __restrict__ Cf, short* __restrict__ Chg, short* __restrict__ Clg,
           short* __restrict__ Vng,
           int M, int N, int K, int NOUT)
{
    constexpr int NJ = NB / 32;
    __shared__ short AhL[2 * 128 * 32];
    __shared__ short BhL[2 * NB * 32];
    __shared__ short BlL[TWOB ? 2 * NB * 32 : 64];

    const int t    = threadIdx.x;
    const int m0   = blockIdx.y * 128;
    const int n0   = blockIdx.x * NB;
    const int wave = t >> 6;
    const int lane = t & 63;
    const int r    = lane & 15;
    const int qd   = lane >> 4;
    const int wm   = (wave & 1) * 64;
    const int wn   = (wave >> 1) * (NB / 2);

    f32x4 acc[4][NJ];
    #pragma unroll
    for (int i = 0; i < 4; ++i)
        #pragma unroll
        for (int j = 0; j < NJ; ++j) acc[i][j] = (f32x4){0.f, 0.f, 0.f, 0.f};

    auto stage = [&](int k0, int buf) {
        const int ao = buf * 4096;
        const int bo = buf * NB * 32;
        #pragma unroll
        for (int s = 0; s < 2; ++s) {
            const int p    = wave * 2 + s;
            const int srow = p * 16 + (lane >> 2);
            const int sg   = (lane & 3) ^ ((srow >> 1) & 3);
            const size_t ga = (size_t)(m0 + srow) * K + k0 + sg * 8;
            gl_lds16(&Ahg[ga], &AhL[ao + p * 512]);
        }
        #pragma unroll
        for (int s = 0; s < NB / 64; ++s) {
            const int p    = wave * (NB / 64) + s;
            const int srow = p * 16 + (lane >> 2);
            const int sg   = (lane & 3) ^ ((srow >> 1) & 3);
            const size_t gb = (size_t)(n0 + srow) * K + k0 + sg * 8;
            gl_lds16(&Bhg[gb], &BhL[bo + p * 512]);
            if constexpr (TWOB) gl_lds16(&Blg[gb], &BlL[bo + p * 512]);
        }
    };

    stage(0, 0);

    const int NT = K / 32;
    for (int kt = 0; kt < NT; ++kt) {
        const int cur = kt & 1;
        __syncthreads();   // stage(kt) landed + prev compute done
        if (kt + 1 < NT) stage((kt + 1) * 32, 1 - cur);

        const int ao = cur * 4096;
        const int bo = cur * NB * 32;
        bf16x8 afh[4], bfh[NJ], bfl[NJ];
        #pragma unroll
        for (int i = 0; i < 4; ++i) {
            const int row = wm + i * 16 + r;
            const int oa = ao + row * 32 + ((qd ^ ((row >> 1) & 3)) * 8);
            afh[i] = __builtin_bit_cast(bf16x8, *(const s16x8*)&AhL[oa]);
        }
        #pragma unroll
        for (int j = 0; j < NJ; ++j) {
            const int row = wn + j * 16 + r;
            const int ob = bo + row * 32 + ((qd ^ ((row >> 1) & 3)) * 8);
            bfh[j] = __builtin_bit_cast(bf16x8, *(const s16x8*)&BhL[ob]);
            if constexpr (TWOB)
                bfl[j] = __builtin_bit_cast(bf16x8, *(const s16x8*)&BlL[ob]);
        }

        #pragma unroll
        for (int i = 0; i < 4; ++i)
            #pragma unroll
            for (int j = 0; j < NJ; ++j) {
                acc[i][j] = __builtin_amdgcn_mfma_f32_16x16x32_bf16(afh[i], bfh[j], acc[i][j], 0, 0, 0);
                if constexpr (TWOB)
                    acc[i][j] = __builtin_amdgcn_mfma_f32_16x16x32_bf16(afh[i], bfl[j], acc[i][j], 0, 0, 0);
            }
    }

    // epilogue: C/D layout col=lane&15, row=quad*4+g
    #pragma unroll
    for (int i = 0; i < 4; ++i)
        #pragma unroll
        for (int j = 0; j < NJ; ++j) {
            const int col = n0 + wn + j * 16 + r;
            if (VT && col >= 2048) {
                // V direct-transposed: Vth[f=col-2048][tok=row], 4 contiguous
                // tokens per thread -> one 8B store.
                s16x4 vv;
                #pragma unroll
                for (int g = 0; g < 4; ++g) vv[g] = f2bf(acc[i][j][g]);
                const int row0 = m0 + wm + i * 16 + qd * 4;
                *(s16x4*)&Vng[(size_t)(col - 2048) * 4096 + row0] = vv;
            } else {
                const float bv = bias ? bias[col] : 0.f;
                #pragma unroll
                for (int g = 0; g < 4; ++g) {
                    const int row = m0 + wm + i * 16 + qd * 4 + g;
                    float x = acc[i][j][g] + bv;
                    if (ACT == 1) x = x / (1.0f + __expf(-x));
                    if (OMODE == 0) {
                        Cf[(size_t)row * NOUT + col] = x;
                    } else if (OMODE == 1) {
                        const short hb = f2bf(x);
                        Chg[(size_t)row * NOUT + col] = hb;
                        Clg[(size_t)row * NOUT + col] = f2bf(x - bf2f(hb));
                    } else {
                        Chg[(size_t)row * NOUT + col] = f2bf(x);
                    }
                }
            }
        }
}

// ---------------------------------------------------------------------------
// MFMA flash attention — r11/r13 kernel verbatim (measured-best, 9
// containers at 115-119us): 3-term QK^T (qh*kh + qh*kl + ql*kh), bit-math
// f2bf_bm, NO setprio, K hi/lo + V double-buffered via global_load_lds,
// 64KB LDS. DO NOT remove work from this kernel: at 2 waves/SIMD it is
// latency-bound and the "redundant" ops cover mask-load/trans/LDS latency
// (r5/r7/r12: hwcvt +26us, setprio +8us, 1-term QK +16us).
// ---------------------------------------------------------------------------
__global__ __launch_bounds__(256, 2)
void attn_mfma3(const short* __restrict__ Xh, const short* __restrict__ Xl,
                const short* __restrict__ Vth, const float* __restrict__ mask,
                short* __restrict__ atth)
{
    __shared__ short KhL[2 * 64 * 64];
    __shared__ short KlL[2 * 64 * 64];
    __shared__ short VhL[2 * 64 * 64];
    __shared__ short PhL[128 * 64];

    const int t    = threadIdx.x;
    const int lane = t & 63;
    const int w    = t >> 6;
    const int r    = lane & 15;
    const int qd   = lane >> 4;
    const int b    = blockIdx.x >> 4;
    const int h    = blockIdx.x & 15;
    const int q0   = blockIdx.y * 128;

    const int srow0 = (lane >> 3);
    const int sgx   = lane & 7;

    bf16x8 qh[2][2], ql[2][2];
    #pragma unroll
    for (int i = 0; i < 2; ++i) {
        const size_t qoff = (size_t)(b * SEQ + q0 + w * 32 + i * 16 + r) * 2048 + h * 64;
        #pragma unroll
        for (int ks = 0; ks < 2; ++ks) {
            qh[i][ks] = __builtin_bit_cast(bf16x8, *(const s16x8*)&Xh[qoff + ks * 32 + qd * 8]);
            ql[i][ks] = __builtin_bit_cast(bf16x8, *(const s16x8*)&Xl[qoff + ks * 32 + qd * 8]);
        }
    }

    s16x8 ones_s;
    #pragma unroll
    for (int c = 0; c < 8; ++c) ones_s[c] = (short)0x3F80;
    const bf16x8 ones = __builtin_bit_cast(bf16x8, ones_s);

    f32x4 O[2][4], Lac[2];
    #pragma unroll
    for (int i = 0; i < 2; ++i) {
        Lac[i] = (f32x4){0.f, 0.f, 0.f, 0.f};
        #pragma unroll
        for (int j = 0; j < 4; ++j) O[i][j] = (f32x4){0.f, 0.f, 0.f, 0.f};
    }

    auto stage = [&](int kt, int buf) {
        const int k0   = kt * 64;
        const int tok0 = b * SEQ + k0;
        const int bo   = buf * 4096;
        #pragma unroll
        for (int s = 0; s < 2; ++s) {
            const int p    = w * 2 + s;
            const int srow = p * 8 + srow0;
            const int sg   = sgx ^ (srow & 7);
            const size_t gk = (size_t)(tok0 + srow) * 2048 + 1024 + h * 64 + sg * 8;
            gl_lds16(&Xh[gk], &KhL[bo + p * 512]);
            gl_lds16(&Xl[gk], &KlL[bo + p * 512]);
            const size_t gv = (size_t)(h * 64 + srow) * 4096 + (size_t)b * SEQ + k0 + sg * 8;
            gl_lds16(&Vth[gv], &VhL[bo + p * 512]);
        }
    };

    stage(0, 0);

    for (int kt = 0; kt < SEQ / 64; ++kt) {
        const int cur = kt & 1;
        const int k0  = kt * 64;

        __syncthreads();
        if (kt + 1 < SEQ / 64) stage(kt + 1, 1 - cur);

        // mask load + fold rescale: m' = m*log2e - 16*log2e
        float mreg[2][4][4];
        #pragma unroll
        for (int i = 0; i < 2; ++i)
            #pragma unroll
            for (int g = 0; g < 4; ++g) {
                const size_t mrow = (size_t)(q0 + w * 32 + i * 16 + qd * 4 + g) * SEQ + k0;
                #pragma unroll
                for (int j = 0; j < 4; ++j)
                    mreg[i][g][j] = fmaf(mask[mrow + j * 16 + r], LOG2E, C_MOFF);
            }

        const int co = cur * 4096;
        f32x4 S[2][4];
        #pragma unroll
        for (int i = 0; i < 2; ++i)
            #pragma unroll
            for (int j = 0; j < 4; ++j) S[i][j] = (f32x4){0.f, 0.f, 0.f, 0.f};
        #pragma unroll
        for (int ks = 0; ks < 2; ++ks) {
            bf16x8 kfh[4], kfl[4];
            #pragma unroll
            for (int j = 0; j < 4; ++j) {
                const int row = j * 16 + r;
                const int off = co + row * 64 + (((ks * 4 + qd) ^ (row & 7)) * 8);
                kfh[j] = __builtin_bit_cast(bf16x8, *(const s16x8*)&KhL[off]);
                kfl[j] = __builtin_bit_cast(bf16x8, *(const s16x8*)&KlL[off]);
            }
            #pragma unroll
            for (int i = 0; i < 2; ++i)
                #pragma unroll
                for (int j = 0; j < 4; ++j) {
                    S[i][j] = __builtin_amdgcn_mfma_f32_16x16x32_bf16(qh[i][ks], kfh[j], S[i][j], 0, 0, 0);
                    S[i][j] = __builtin_amdgcn_mfma_f32_16x16x32_bf16(qh[i][ks], kfl[j], S[i][j], 0, 0, 0);
                    S[i][j] = __builtin_amdgcn_mfma_f32_16x16x32_bf16(ql[i][ks], kfh[j], S[i][j], 0, 0, 0);
                }
        }

        // p = exp2(s * 0.125*log2e + m')
        #pragma unroll
        for (int i = 0; i < 2; ++i)
            #pragma unroll
            for (int j = 0; j < 4; ++j)
                #pragma unroll
                for (int g = 0; g < 4; ++g)
                    S[i][j][g] = exp2f(fmaf(S[i][j][g], C_SCALE, mreg[i][g][j]));

        #pragma unroll
        for (int i = 0; i < 2; ++i)
            #pragma unroll
            for (int j = 0; j < 4; ++j)
                #pragma unroll
                for (int g = 0; g < 4; ++g) {
                    const int prow = w * 32 + i * 16 + qd * 4 + g;
                    const int gr   = (j * 2 + (r >> 3)) ^ ((prow >> 1) & 7);
                    PhL[prow * 64 + gr * 8 + (r & 7)] = f2bf_bm(S[i][j][g]);
                }

        #pragma unroll
        for (int ks = 0; ks < 2; ++ks) {
            bf16x8 pfh[2], vfh[4];
            #pragma unroll
            for (int i = 0; i < 2; ++i) {
                const int row = w * 32 + i * 16 + r;
                pfh[i] = __builtin_bit_cast(bf16x8,
                    *(const s16x8*)&PhL[row * 64 + (((ks * 4 + qd) ^ ((row >> 1) & 7)) * 8)]);
            }
            #pragma unroll
            for (int j = 0; j < 4; ++j) {
                const int row = j * 16 + r;
                vfh[j] = __builtin_bit_cast(bf16x8,
                    *(const s16x8*)&VhL[co + row * 64 + (((ks * 4 + qd) ^ (row & 7)) * 8)]);
            }
            #pragma unroll
            for (int i = 0; i < 2; ++i) {
                Lac[i] = __builtin_amdgcn_mfma_f32_16x16x32_bf16(pfh[i], ones, Lac[i], 0, 0, 0);
                #pragma unroll
                for (int j = 0; j < 4; ++j)
                    O[i][j] = __builtin_amdgcn_mfma_f32_16x16x32_bf16(pfh[i], vfh[j], O[i][j], 0, 0, 0);
            }
        }
    }

    #pragma unroll
    for (int i = 0; i < 2; ++i)
        #pragma unroll
        for (int g = 0; g < 4; ++g) {
            const float inv = 1.0f / Lac[i][g];
            const size_t row = (size_t)(b * SEQ + q0 + w * 32 + i * 16 + qd * 4 + g);
            #pragma unroll
            for (int j = 0; j < 4; ++j)
                atth[row * 1024 + h * 64 + j * 16 + r] = f2bf_bm(O[i][j][g] * inv);
        }
}

// ---------------------------------------------------------------------------
extern "C" void kernel_launch(void* const* d_in, const int* in_sizes, int n_in,
                              void* d_out, int out_size, void* d_ws, size_t ws_size,
                              hipStream_t stream)
{
    const float* seq  = (const float*)d_in[0];
    const float* mask = (const float*)d_in[1];
    const float* Wqkv = (const float*)d_in[2];
    const float* W1   = (const float*)d_in[3];
    const float* b1   = (const float*)d_in[4];
    const float* W2   = (const float*)d_in[5];
    const float* b2   = (const float*)d_in[6];
    float* out = (float*)d_out;

    // ws (64 MiB): Xh[0,16) Xl[16,32) Wt2h[32,36) Wt1h[40,44) WtQh[48,54)
    //   after attn: hidh[0,16) (overlays Xh, dead after P3)
    // d_out (16 MiB): seqh[0,8) (P0->P1) -> atth[0,8) (P3->P4);
    //                 Vth[8,16) (P1->P3); out[0,16) (P5).
    const size_t MiB = 1048576;
    char* B = (char*)d_ws;
    short* Xh   = (short*)(B + 0);
    short* Xl   = (short*)(B + 16 * MiB);
    short* Wt2h = (short*)(B + 32 * MiB);
    short* Wt1h = (short*)(B + 40 * MiB);
    short* WtQh = (short*)(B + 48 * MiB);
    short* hidh = (short*)(B + 0);

    short* seqh = (short*)d_out;
    short* atth = (short*)d_out;
    short* Vth  = (short*)((char*)d_out + 8 * MiB);

    // P0: seq hi-split + Wqkv/W1/W2 hi-only transpose-splits
    prep_kernel<<<8192, 256, 0, stream>>>(seq, seqh, Wqkv, WtQh,
                                          W1, Wt1h, W2, Wt2h);

    // P1: QKV (1-term weights, fp32 acc) — Q|K split -> Xh/Xl,
    //     V direct-transposed -> Vth
    gemm2<0, 1, 1, 128, false><<<dim3(3072 / 128, MTOT / 128), 256, 0, stream>>>(
        seqh, WtQh, nullptr, nullptr,
        nullptr, Xh, Xl, Vth, MTOT, 3072, 1024, 2048);

    // P3: flash attention (3-term QK^T, verbatim) -> atth in d_out
    attn_mfma3<<<dim3(BSZ * NHEAD, SEQ / 128), 256, 0, stream>>>(Xh, Xl, Vth, mask, atth);

    // P4: FFN1 + SiLU (1-term) -> hidh
    gemm2<1, 2, 0, 128, false><<<dim3(2048 / 128, MTOT / 128), 256, 0, stream>>>(
        atth, Wt1h, nullptr, b1,
        nullptr, hidh, nullptr, nullptr, MTOT, 2048, 1024, 2048);

    // P5: FFN2 + bias (1-term) -> out
    gemm2<0, 0, 0, 64, false><<<dim3(1024 / 64, MTOT / 128), 256, 0, stream>>>(
        hidh, Wt2h, nullptr, b2,
        out, nullptr, nullptr, nullptr, MTOT, 1024, 2048, 1024);
}

// Round 16
// 309.946 us; speedup vs baseline: 1.0233x; 1.0233x over previous
//
#include <hip/hip_runtime.h>
#include <math.h>

#define SEQ   2048
#define NHEAD 16
#define HD    64
#define BSZ   2
#define MTOT  (BSZ*SEQ)   // 4096

#define LOG2E    1.4426950408889634f
#define C_SCALE  0.18033688011112043f    // 0.125 * log2(e)
#define C_MOFF  -23.083120654223414f     // -16 * log2(e)

typedef __bf16 bf16x8 __attribute__((ext_vector_type(8)));
typedef short  s16x8  __attribute__((ext_vector_type(8)));
typedef short  s16x4  __attribute__((ext_vector_type(4)));
typedef float  f32x4  __attribute__((ext_vector_type(4)));

// fp32 -> bf16 RNE, hardware cvt. Use in issue-bound kernels (gemm epilogue,
// prep).
__device__ __forceinline__ short f2bf(float x) {
    return __builtin_bit_cast(short, (__bf16)x);
}
// fp32 -> bf16 RNE, bit-math. Used in the LATENCY-BOUND attn kernel
// (2 waves/SIMD): extra int ops fill trans/LDS latency for free.
// attn ledger: bitmath/nosp 3-term = 115-119 (10 containers) — every
// work-removal variant regressed (hwcvt +26, setprio +8, 1-term QK +16:
// the "redundant" ops were covering mask-load/trans latency). This round
// attacks the latency SOURCE (mask loads) while keeping all filler.
__device__ __forceinline__ short f2bf_bm(float x) {
    unsigned u = __builtin_bit_cast(unsigned, x);
    u = (u + 0x7fffu + ((u >> 16) & 1u)) >> 16;
    return (short)u;
}
__device__ __forceinline__ float bf2f(short h) {
    unsigned u = ((unsigned)(unsigned short)h) << 16;
    return __builtin_bit_cast(float, u);
}

// async global->LDS 16B: dest = wave-uniform lds base + lane*16
__device__ __forceinline__ void gl_lds16(const short* g, short* l) {
    __builtin_amdgcn_global_load_lds(
        (const __attribute__((address_space(1))) unsigned int*)g,
        (__attribute__((address_space(3))) unsigned int*)l, 16, 0, 0);
}

// ---------------------------------------------------------------------------
// Transpose+split one 32x32 tile: W[K,N] fp32 -> Th (+Tl if non-null)
// [N,K] bf16 hi/lo
// ---------------------------------------------------------------------------
__device__ __forceinline__ void tsplit_tile(const float* __restrict__ W,
    short* __restrict__ Th, short* __restrict__ Tl,
    int K, int N, int k0, int n0, float (*T)[33], int t)
{
    {
        const int kl = t >> 3;
        const int nl = (t & 7) * 4;
        const float4 v = *(const float4*)&W[(size_t)(k0 + kl) * N + n0 + nl];
        T[nl + 0][kl] = v.x; T[nl + 1][kl] = v.y;
        T[nl + 2][kl] = v.z; T[nl + 3][kl] = v.w;
    }
    __syncthreads();
    {
        const int nl = t >> 3;
        const int kl = (t & 7) * 4;
        s16x4 h, l;
        #pragma unroll
        for (int c = 0; c < 4; ++c) {
            const float x = T[nl][kl + c];
            const short hb = f2bf(x);
            h[c] = hb;
            l[c] = f2bf(x - bf2f(hb));
        }
        const size_t o = (size_t)(n0 + nl) * K + k0 + kl;
        *(s16x4*)&Th[o] = h;
        if (Tl) *(s16x4*)&Tl[o] = l;
    }
}

// ---------------------------------------------------------------------------
// prep: [0,1024) seq -> seqh (bf16 hi only);
//       [1024,4096) Wqkv hi only; [4096,6144) W1 hi only;
//       [6144,8192) W2 hi only;
//       [8192,9216) mask -> Mp: PERMUTED bf16 mask.
//         Mp[row][kb*64 + r*4 + j] = f2bf(mask[row][kb*64 + j*16 + r])
//         so an attn lane's 4 per-tile mask values are 4 contiguous bf16
//         (one 8B load instead of 4 stride-16 dword loads).
// ---------------------------------------------------------------------------
__global__ __launch_bounds__(256)
void prep_kernel(const float* __restrict__ seq, short* __restrict__ seqh,
                 const float* __restrict__ Wqkv, short* __restrict__ WtQh,
                 const float* __restrict__ W1, short* __restrict__ Wt1h,
                 const float* __restrict__ W2, short* __restrict__ Wt2h,
                 const float* __restrict__ mask, short* __restrict__ Mp)
{
    __shared__ float T[32][33];
    const int t = threadIdx.x;
    const int bid = blockIdx.x;
    if (bid < 1024) {
        const size_t base = (size_t)bid * 4096 + (size_t)t * 16;
        #pragma unroll
        for (int c = 0; c < 4; ++c) {
            const float4 v = *(const float4*)&seq[base + c * 4];
            s16x4 h;
            h[0] = f2bf(v.x); h[1] = f2bf(v.y); h[2] = f2bf(v.z); h[3] = f2bf(v.w);
            *(s16x4*)&seqh[base + c * 4] = h;
        }
    } else if (bid < 4096) {
        const int idx = bid - 1024;
        tsplit_tile(Wqkv, WtQh, nullptr, 1024, 3072, (idx & 31) * 32, (idx >> 5) * 32, T, t);
    } else if (bid < 6144) {
        const int idx = bid - 4096;
        tsplit_tile(W1, Wt1h, nullptr, 1024, 2048, (idx & 31) * 32, (idx >> 5) * 32, T, t);
    } else if (bid < 8192) {
        const int idx = bid - 6144;
        tsplit_tile(W2, Wt2h, nullptr, 2048, 1024, (idx & 63) * 32, (idx >> 6) * 32, T, t);
    } else {
        // mask permute+bf16: 2 rows per block, 16 output elems per thread
        const int idx = bid - 8192;
        const int row = idx * 2 + (t >> 7);
        const int oc  = (t & 127) * 16;          // output col base (16-aligned)
        const int kb  = oc >> 6;                 // 64-col block
        const int w0  = oc & 63;                 // position within block
        const size_t ibase = (size_t)row * 2048 + kb * 64;
        s16x8 o0, o1;
        #pragma unroll
        for (int m = 0; m < 16; ++m) {
            const int w = w0 + m;                // p = r*4+j
            const float v = mask[ibase + (w & 3) * 16 + (w >> 2)];
            if (m < 8) o0[m] = f2bf(v); else o1[m - 8] = f2bf(v);
        }
        *(s16x8*)&Mp[(size_t)row * 2048 + oc]     = o0;
        *(s16x8*)&Mp[(size_t)row * 2048 + oc + 8] = o1;
    }
}

// ---------------------------------------------------------------------------
// split MFMA GEMM v8 (r13 verbatim — best measured config, 312.3us):
// BK=32 double-buffered, all 1-term, __launch_bounds__(256,2)
// (r15's (256,4) was neutral-to-negative; r14's BK=64/fusion neutral).
// V direct-transposed store in VT epilogue.
// OMODE: 0 fp32 out, 1 split hi/lo out, 2 hi-only out. ACT 1: SiLU.
// ---------------------------------------------------------------------------
template<int ACT, int OMODE, int VT, int NB, bool TWOB>
__global__ __launch_bounds__(256, 2)
void gemm2(const short* __restrict__ Ahg,
           const short* __restrict__ Bhg, const short* __restrict__ Blg,
           const float* __restrict__ bias,
           float* __restrict__ Cf, short* __restrict__ Chg, short* __restrict__ Clg,
           short* __restrict__ Vng,
           int M, int N, int K, int NOUT)
{
    constexpr int NJ = NB / 32;
    __shared__ short AhL[2 * 128 * 32];
    __shared__ short BhL[2 * NB * 32];
    __shared__ short BlL[TWOB ? 2 * NB * 32 : 64];

    const int t    = threadIdx.x;
    const int m0   = blockIdx.y * 128;
    const int n0   = blockIdx.x * NB;
    const int wave = t >> 6;
    const int lane = t & 63;
    const int r    = lane & 15;
    const int qd   = lane >> 4;
    const int wm   = (wave & 1) * 64;
    const int wn   = (wave >> 1) * (NB / 2);

    f32x4 acc[4][NJ];
    #pragma unroll
    for (int i = 0; i < 4; ++i)
        #pragma unroll
        for (int j = 0; j < NJ; ++j) acc[i][j] = (f32x4){0.f, 0.f, 0.f, 0.f};

    auto stage = [&](int k0, int buf) {
        const int ao = buf * 4096;
        const int bo = buf * NB * 32;
        #pragma unroll
        for (int s = 0; s < 2; ++s) {
            const int p    = wave * 2 + s;
            const int srow = p * 16 + (lane >> 2);
            const int sg   = (lane & 3) ^ ((srow >> 1) & 3);
            const size_t ga = (size_t)(m0 + srow) * K + k0 + sg * 8;
            gl_lds16(&Ahg[ga], &AhL[ao + p * 512]);
        }
        #pragma unroll
        for (int s = 0; s < NB / 64; ++s) {
            const int p    = wave * (NB / 64) + s;
            const int srow = p * 16 + (lane >> 2);
            const int sg   = (lane & 3) ^ ((srow >> 1) & 3);
            const size_t gb = (size_t)(n0 + srow) * K + k0 + sg * 8;
            gl_lds16(&Bhg[gb], &BhL[bo + p * 512]);
            if constexpr (TWOB) gl_lds16(&Blg[gb], &BlL[bo + p * 512]);
        }
    };

    stage(0, 0);

    const int NT = K / 32;
    for (int kt = 0; kt < NT; ++kt) {
        const int cur = kt & 1;
        __syncthreads();   // stage(kt) landed + prev compute done
        if (kt + 1 < NT) stage((kt + 1) * 32, 1 - cur);

        const int ao = cur * 4096;
        const int bo = cur * NB * 32;
        bf16x8 afh[4], bfh[NJ], bfl[NJ];
        #pragma unroll
        for (int i = 0; i < 4; ++i) {
            const int row = wm + i * 16 + r;
            const int oa = ao + row * 32 + ((qd ^ ((row >> 1) & 3)) * 8);
            afh[i] = __builtin_bit_cast(bf16x8, *(const s16x8*)&AhL[oa]);
        }
        #pragma unroll
        for (int j = 0; j < NJ; ++j) {
            const int row = wn + j * 16 + r;
            const int ob = bo + row * 32 + ((qd ^ ((row >> 1) & 3)) * 8);
            bfh[j] = __builtin_bit_cast(bf16x8, *(const s16x8*)&BhL[ob]);
            if constexpr (TWOB)
                bfl[j] = __builtin_bit_cast(bf16x8, *(const s16x8*)&BlL[ob]);
        }

        #pragma unroll
        for (int i = 0; i < 4; ++i)
            #pragma unroll
            for (int j = 0; j < NJ; ++j) {
                acc[i][j] = __builtin_amdgcn_mfma_f32_16x16x32_bf16(afh[i], bfh[j], acc[i][j], 0, 0, 0);
                if constexpr (TWOB)
                    acc[i][j] = __builtin_amdgcn_mfma_f32_16x16x32_bf16(afh[i], bfl[j], acc[i][j], 0, 0, 0);
            }
    }

    // epilogue: C/D layout col=lane&15, row=quad*4+g
    #pragma unroll
    for (int i = 0; i < 4; ++i)
        #pragma unroll
        for (int j = 0; j < NJ; ++j) {
            const int col = n0 + wn + j * 16 + r;
            if (VT && col >= 2048) {
                // V direct-transposed: Vth[f=col-2048][tok=row], 4 contiguous
                // tokens per thread -> one 8B store.
                s16x4 vv;
                #pragma unroll
                for (int g = 0; g < 4; ++g) vv[g] = f2bf(acc[i][j][g]);
                const int row0 = m0 + wm + i * 16 + qd * 4;
                *(s16x4*)&Vng[(size_t)(col - 2048) * 4096 + row0] = vv;
            } else {
                const float bv = bias ? bias[col] : 0.f;
                #pragma unroll
                for (int g = 0; g < 4; ++g) {
                    const int row = m0 + wm + i * 16 + qd * 4 + g;
                    float x = acc[i][j][g] + bv;
                    if (ACT == 1) x = x / (1.0f + __expf(-x));
                    if (OMODE == 0) {
                        Cf[(size_t)row * NOUT + col] = x;
                    } else if (OMODE == 1) {
                        const short hb = f2bf(x);
                        Chg[(size_t)row * NOUT + col] = hb;
                        Clg[(size_t)row * NOUT + col] = f2bf(x - bf2f(hb));
                    } else {
                        Chg[(size_t)row * NOUT + col] = f2bf(x);
                    }
                }
            }
        }
}

// ---------------------------------------------------------------------------
// MFMA flash attention v12 = measured-best structure (3-term QK^T, bit-math
// f2bf_bm, NO setprio, dbuf K/V via global_load_lds, 64KB LDS) with the
// mask-load LATENCY SOURCE shrunk: permuted bf16 mask Mp gives each lane
// its 4 per-tile values as one 8B load — 32 scalar dword loads/tile ->
// 8x 8B loads (4x fewer VMEM issues, half the bytes, coalesced).
// All filler (fmaf, bf2f shifts, 3-term MFMA) preserved — the ledger says
// the filler is load-bearing; only the covered latency shrinks.
// ---------------------------------------------------------------------------
__global__ __launch_bounds__(256, 2)
void attn_mfma3(const short* __restrict__ Xh, const short* __restrict__ Xl,
                const short* __restrict__ Vth, const short* __restrict__ Mp,
                short* __restrict__ atth)
{
    __shared__ short KhL[2 * 64 * 64];
    __shared__ short KlL[2 * 64 * 64];
    __shared__ short VhL[2 * 64 * 64];
    __shared__ short PhL[128 * 64];

    const int t    = threadIdx.x;
    const int lane = t & 63;
    const int w    = t >> 6;
    const int r    = lane & 15;
    const int qd   = lane >> 4;
    const int b    = blockIdx.x >> 4;
    const int h    = blockIdx.x & 15;
    const int q0   = blockIdx.y * 128;

    const int srow0 = (lane >> 3);
    const int sgx   = lane & 7;

    bf16x8 qh[2][2], ql[2][2];
    #pragma unroll
    for (int i = 0; i < 2; ++i) {
        const size_t qoff = (size_t)(b * SEQ + q0 + w * 32 + i * 16 + r) * 2048 + h * 64;
        #pragma unroll
        for (int ks = 0; ks < 2; ++ks) {
            qh[i][ks] = __builtin_bit_cast(bf16x8, *(const s16x8*)&Xh[qoff + ks * 32 + qd * 8]);
            ql[i][ks] = __builtin_bit_cast(bf16x8, *(const s16x8*)&Xl[qoff + ks * 32 + qd * 8]);
        }
    }

    s16x8 ones_s;
    #pragma unroll
    for (int c = 0; c < 8; ++c) ones_s[c] = (short)0x3F80;
    const bf16x8 ones = __builtin_bit_cast(bf16x8, ones_s);

    f32x4 O[2][4], Lac[2];
    #pragma unroll
    for (int i = 0; i < 2; ++i) {
        Lac[i] = (f32x4){0.f, 0.f, 0.f, 0.f};
        #pragma unroll
        for (int j = 0; j < 4; ++j) O[i][j] = (f32x4){0.f, 0.f, 0.f, 0.f};
    }

    auto stage = [&](int kt, int buf) {
        const int k0   = kt * 64;
        const int tok0 = b * SEQ + k0;
        const int bo   = buf * 4096;
        #pragma unroll
        for (int s = 0; s < 2; ++s) {
            const int p    = w * 2 + s;
            const int srow = p * 8 + srow0;
            const int sg   = sgx ^ (srow & 7);
            const size_t gk = (size_t)(tok0 + srow) * 2048 + 1024 + h * 64 + sg * 8;
            gl_lds16(&Xh[gk], &KhL[bo + p * 512]);
            gl_lds16(&Xl[gk], &KlL[bo + p * 512]);
            const size_t gv = (size_t)(h * 64 + srow) * 4096 + (size_t)b * SEQ + k0 + sg * 8;
            gl_lds16(&Vth[gv], &VhL[bo + p * 512]);
        }
    };

    stage(0, 0);

    for (int kt = 0; kt < SEQ / 64; ++kt) {
        const int cur = kt & 1;
        const int k0  = kt * 64;

        __syncthreads();
        if (kt + 1 < SEQ / 64) stage(kt + 1, 1 - cur);

        // mask load (permuted bf16: 4 contiguous values per lane-row) +
        // fold rescale: m' = m*log2e - 16*log2e
        float mreg[2][4][4];
        #pragma unroll
        for (int i = 0; i < 2; ++i)
            #pragma unroll
            for (int g = 0; g < 4; ++g) {
                const size_t mrow = (size_t)(q0 + w * 32 + i * 16 + qd * 4 + g) * 2048 + k0 + r * 4;
                const s16x4 mv = *(const s16x4*)&Mp[mrow];
                #pragma unroll
                for (int j = 0; j < 4; ++j)
                    mreg[i][g][j] = fmaf(bf2f(mv[j]), LOG2E, C_MOFF);
            }

        const int co = cur * 4096;
        f32x4 S[2][4];
        #pragma unroll
        for (int i = 0; i < 2; ++i)
            #pragma unroll
            for (int j = 0; j < 4; ++j) S[i][j] = (f32x4){0.f, 0.f, 0.f, 0.f};
        #pragma unroll
        for (int ks = 0; ks < 2; ++ks) {
            bf16x8 kfh[4], kfl[4];
            #pragma unroll
            for (int j = 0; j < 4; ++j) {
                const int row = j * 16 + r;
                const int off = co + row * 64 + (((ks * 4 + qd) ^ (row & 7)) * 8);
                kfh[j] = __builtin_bit_cast(bf16x8, *(const s16x8*)&KhL[off]);
                kfl[j] = __builtin_bit_cast(bf16x8, *(const s16x8*)&KlL[off]);
            }
            #pragma unroll
            for (int i = 0; i < 2; ++i)
                #pragma unroll
                for (int j = 0; j < 4; ++j) {
                    S[i][j] = __builtin_amdgcn_mfma_f32_16x16x32_bf16(qh[i][ks], kfh[j], S[i][j], 0, 0, 0);
                    S[i][j] = __builtin_amdgcn_mfma_f32_16x16x32_bf16(qh[i][ks], kfl[j], S[i][j], 0, 0, 0);
                    S[i][j] = __builtin_amdgcn_mfma_f32_16x16x32_bf16(ql[i][ks], kfh[j], S[i][j], 0, 0, 0);
                }
        }

        // p = exp2(s * 0.125*log2e + m')
        #pragma unroll
        for (int i = 0; i < 2; ++i)
            #pragma unroll
            for (int j = 0; j < 4; ++j)
                #pragma unroll
                for (int g = 0; g < 4; ++g)
                    S[i][j][g] = exp2f(fmaf(S[i][j][g], C_SCALE, mreg[i][g][j]));

        #pragma unroll
        for (int i = 0; i < 2; ++i)
            #pragma unroll
            for (int j = 0; j < 4; ++j)
                #pragma unroll
                for (int g = 0; g < 4; ++g) {
                    const int prow = w * 32 + i * 16 + qd * 4 + g;
                    const int gr   = (j * 2 + (r >> 3)) ^ ((prow >> 1) & 7);
                    PhL[prow * 64 + gr * 8 + (r & 7)] = f2bf_bm(S[i][j][g]);
                }

        #pragma unroll
        for (int ks = 0; ks < 2; ++ks) {
            bf16x8 pfh[2], vfh[4];
            #pragma unroll
            for (int i = 0; i < 2; ++i) {
                const int row = w * 32 + i * 16 + r;
                pfh[i] = __builtin_bit_cast(bf16x8,
                    *(const s16x8*)&PhL[row * 64 + (((ks * 4 + qd) ^ ((row >> 1) & 7)) * 8)]);
            }
            #pragma unroll
            for (int j = 0; j < 4; ++j) {
                const int row = j * 16 + r;
                vfh[j] = __builtin_bit_cast(bf16x8,
                    *(const s16x8*)&VhL[co + row * 64 + (((ks * 4 + qd) ^ (row & 7)) * 8)]);
            }
            #pragma unroll
            for (int i = 0; i < 2; ++i) {
                Lac[i] = __builtin_amdgcn_mfma_f32_16x16x32_bf16(pfh[i], ones, Lac[i], 0, 0, 0);
                #pragma unroll
                for (int j = 0; j < 4; ++j)
                    O[i][j] = __builtin_amdgcn_mfma_f32_16x16x32_bf16(pfh[i], vfh[j], O[i][j], 0, 0, 0);
            }
        }
    }

    #pragma unroll
    for (int i = 0; i < 2; ++i)
        #pragma unroll
        for (int g = 0; g < 4; ++g) {
            const float inv = 1.0f / Lac[i][g];
            const size_t row = (size_t)(b * SEQ + q0 + w * 32 + i * 16 + qd * 4 + g);
            #pragma unroll
            for (int j = 0; j < 4; ++j)
                atth[row * 1024 + h * 64 + j * 16 + r] = f2bf_bm(O[i][j][g] * inv);
        }
}

// ---------------------------------------------------------------------------
extern "C" void kernel_launch(void* const* d_in, const int* in_sizes, int n_in,
                              void* d_out, int out_size, void* d_ws, size_t ws_size,
                              hipStream_t stream)
{
    const float* seq  = (const float*)d_in[0];
    const float* mask = (const float*)d_in[1];
    const float* Wqkv = (const float*)d_in[2];
    const float* W1   = (const float*)d_in[3];
    const float* b1   = (const float*)d_in[4];
    const float* W2   = (const float*)d_in[5];
    const float* b2   = (const float*)d_in[6];
    float* out = (float*)d_out;

    // ws (64 MiB): Xh[0,16) Xl[16,32) Wt2h[32,36) Wt1h[40,44) WtQh[48,54)
    //              Mp[54,62) (permuted bf16 mask, P0 -> P3)
    //   after attn: hidh[0,16) (overlays Xh, dead after P3)
    // d_out (16 MiB): seqh[0,8) (P0->P1) -> atth[0,8) (P3->P4);
    //                 Vth[8,16) (P1->P3); out[0,16) (P5).
    const size_t MiB = 1048576;
    char* B = (char*)d_ws;
    short* Xh   = (short*)(B + 0);
    short* Xl   = (short*)(B + 16 * MiB);
    short* Wt2h = (short*)(B + 32 * MiB);
    short* Wt1h = (short*)(B + 40 * MiB);
    short* WtQh = (short*)(B + 48 * MiB);
    short* Mp   = (short*)(B + 54 * MiB);
    short* hidh = (short*)(B + 0);

    short* seqh = (short*)d_out;
    short* atth = (short*)d_out;
    short* Vth  = (short*)((char*)d_out + 8 * MiB);

    // P0: seq hi-split + Wqkv/W1/W2 hi-only tsplits + mask permute->bf16
    prep_kernel<<<9216, 256, 0, stream>>>(seq, seqh, Wqkv, WtQh,
                                          W1, Wt1h, W2, Wt2h, mask, Mp);

    // P1: QKV (1-term weights, fp32 acc) — Q|K split -> Xh/Xl,
    //     V direct-transposed -> Vth
    gemm2<0, 1, 1, 128, false><<<dim3(3072 / 128, MTOT / 128), 256, 0, stream>>>(
        seqh, WtQh, nullptr, nullptr,
        nullptr, Xh, Xl, Vth, MTOT, 3072, 1024, 2048);

    // P3: flash attention (3-term QK^T, permuted bf16 mask) -> atth
    attn_mfma3<<<dim3(BSZ * NHEAD, SEQ / 128), 256, 0, stream>>>(Xh, Xl, Vth, Mp, atth);

    // P4: FFN1 + SiLU (1-term) -> hidh
    gemm2<1, 2, 0, 128, false><<<dim3(2048 / 128, MTOT / 128), 256, 0, stream>>>(
        atth, Wt1h, nullptr, b1,
        nullptr, hidh, nullptr, nullptr, MTOT, 2048, 1024, 2048);

    // P5: FFN2 + bias (1-term) -> out
    gemm2<0, 0, 0, 64, false><<<dim3(1024 / 64, MTOT / 128), 256, 0, stream>>>(
        hidh, Wt2h, nullptr, b2,
        out, nullptr, nullptr, nullptr, MTOT, 1024, 2048, 1024);
}